// Round 10
// baseline (212.085 us; speedup 1.0000x reference)
//
#include <hip/hip_runtime.h>

#define NN 100000
#define NE 800000
#define NI 1600000      // items = 2E (both directions)
#define NB 391          // coarse buckets = ceil(2N / 512)
#define IPB 6250        // items per block in hist/scatter (256 blocks)

// grid split for fused prep kernel
#define GB_CVT 12500    // cvt_x blocks (NN*32 float4 / 256)
#define GB_PW  128      // prep_w blocks
#define GB_HIST 256     // hist blocks

// ---- workspace layout (bytes) ----
#define OFF_INV    0u           // float[2N]   [0,N)=row-keyed inv, [N,2N)=col-keyed inv
#define OFF_OFFS   800000u      // int[2N+1]
#define OFF_BB     1600008u     // int[NB+1]
#define OFF_HIST   1601600u     // int[NB*256]
#define OFF_CSRC   2001984u     // int[2E]
#define OFF_XB     8401984u     // bf16[N*128]
#define OFF_PAIRS  34001984u    // ulong[2E]
#define OFF_WT     85201984u    // bf16[128*256] WT[c][k]: k<128 -> W_ds, else W_sd
#define OFF_BIAS   85267520u    // float[128] 0.5*(b_ds+b_sd)
#define OFF_TOT    85268032u    // int[NB]

typedef short short8 __attribute__((ext_vector_type(8)));
typedef unsigned short u16x8 __attribute__((ext_vector_type(8)));
typedef float f32x4 __attribute__((ext_vector_type(4)));
typedef float f32x8 __attribute__((ext_vector_type(8)));

__device__ __forceinline__ unsigned short f2bf(float f) {
    unsigned u = __float_as_uint(f);
    u = (u + 0x7FFFu + ((u >> 16) & 1u)) >> 16;   // RNE
    return (unsigned short)u;
}
__device__ __forceinline__ float b2f(unsigned short h) {
    return __uint_as_float(((unsigned)h) << 16);
}
__device__ __forceinline__ f32x8 bvec2f(u16x8 v) {
    f32x8 r;
#pragma unroll
    for (int i = 0; i < 8; ++i) r[i] = b2f(v[i]);
    return r;
}

// item i: i<NE  -> key=row=ei[i],      val=col=ei[NE+i]  (in-agg, keyed by row)
//         i>=NE -> key=NN+col=NN+ei[i], val=row=ei[i-NE] (out-agg, keyed by col)

// Fused: cvt_x (blocks [0,GB_CVT)) | prep_w | hist  — mutually independent work
__global__ __launch_bounds__(256) void k_prep(
    const float4* __restrict__ x4, ushort4* __restrict__ xb4,
    const float* __restrict__ Wds, const float* __restrict__ Wsd,
    const float* __restrict__ bds, const float* __restrict__ bsd,
    unsigned short* __restrict__ wt, float* __restrict__ bias,
    const int* __restrict__ ei, int* __restrict__ hist) {
    __shared__ int h[NB];
    int bid = blockIdx.x;
    if (bid < GB_CVT) {
        int i = bid * 256 + threadIdx.x;           // < NN*32 exactly
        float4 v = x4[i];
        ushort4 o;
        o.x = f2bf(v.x); o.y = f2bf(v.y); o.z = f2bf(v.z); o.w = f2bf(v.w);
        xb4[i] = o;
        return;
    }
    if (bid < GB_CVT + GB_PW) {
        int id = (bid - GB_CVT) * 256 + threadIdx.x;   // < 32768 exactly
        int c = id & 127;
        int k = id >> 7;
        float v = (k < 128) ? Wds[k * 128 + c] : Wsd[(k - 128) * 128 + c];
        wt[c * 256 + k] = f2bf(v);
        if (k == 0) bias[c] = 0.5f * (bds[c] + bsd[c]);
        return;
    }
    int hb = bid - GB_CVT - GB_PW;                  // hist block 0..255
    for (int k = threadIdx.x; k < NB; k += 256) h[k] = 0;
    __syncthreads();
    int base = hb * IPB;
    for (int t = threadIdx.x; t < IPB; t += 256) {
        int i = base + t;
        int key = (i < NE) ? ei[i] : (NN + ei[i]);
        atomicAdd(&h[key >> 9], 1);
    }
    __syncthreads();
    for (int k = threadIdx.x; k < NB; k += 256) hist[k * 256 + hb] = h[k];
}

// tot[k] = sum_b hist[k][b]
__global__ __launch_bounds__(256) void k_red(const int* __restrict__ hist,
                                             int* __restrict__ tot) {
    __shared__ int s[256];
    int k = blockIdx.x;
    s[threadIdx.x] = hist[k * 256 + threadIdx.x];
    __syncthreads();
    for (int st = 128; st > 0; st >>= 1) {
        if (threadIdx.x < st) s[threadIdx.x] += s[threadIdx.x + st];
        __syncthreads();
    }
    if (threadIdx.x == 0) tot[k] = s[0];
}

// bb = exclusive scan of tot (NB entries, padded to 512)
__global__ __launch_bounds__(512) void k_scan_tot(const int* __restrict__ tot,
                                                  int* __restrict__ bb) {
    __shared__ int sA[512], sB[512];
    int tid = threadIdx.x;
    int v = (tid < NB) ? tot[tid] : 0;
    sA[tid] = v;
    __syncthreads();
    int *src = sA, *dst = sB;
    for (int st = 1; st < 512; st <<= 1) {
        dst[tid] = src[tid] + ((tid >= st) ? src[tid - st] : 0);
        __syncthreads();
        int* tp = src; src = dst; dst = tp;
    }
    if (tid <= NB) bb[tid] = (tid > 0) ? src[tid - 1] : 0;
}

// hist[k][b] = bb[k] + exclusive_scan_b(hist[k][*])
__global__ __launch_bounds__(256) void k_rebase(int* __restrict__ hist,
                                                const int* __restrict__ bb) {
    __shared__ int sA[256], sB[256];
    int k = blockIdx.x, tid = threadIdx.x;
    int v = hist[k * 256 + tid];
    sA[tid] = v;
    __syncthreads();
    int *src = sA, *dst = sB;
    for (int st = 1; st < 256; st <<= 1) {
        dst[tid] = src[tid] + ((tid >= st) ? src[tid - st] : 0);
        __syncthreads();
        int* tp = src; src = dst; dst = tp;
    }
    hist[k * 256 + tid] = bb[k] + src[tid] - v;   // exclusive
}

__global__ __launch_bounds__(256) void k_scatter(const int* __restrict__ ei,
                                                 const int* __restrict__ hist,
                                                 unsigned long long* __restrict__ pairs) {
    __shared__ int cur[NB];
    for (int k = threadIdx.x; k < NB; k += 256) cur[k] = hist[k * 256 + blockIdx.x];
    __syncthreads();
    int base = blockIdx.x * IPB;
    for (int t = threadIdx.x; t < IPB; t += 256) {
        int i = base + t;
        int e = ei[i];
        int key, val;
        if (i < NE) { key = e;      val = ei[NE + i]; }
        else        { key = NN + e; val = ei[i - NE]; }
        int pos = atomicAdd(&cur[key >> 9], 1);
        pairs[pos] = (((unsigned long long)(unsigned)key) << 32) | (unsigned)val;
    }
}

// one block per bucket: count 512 local keys, scan, emit offsets+inv, scatter vals
__global__ __launch_bounds__(256) void k_bucket(const unsigned long long* __restrict__ pairs,
                                                const int* __restrict__ bb,
                                                int* __restrict__ csr_src,
                                                int* __restrict__ offsets,
                                                float* __restrict__ inv) {
    __shared__ int sA[512], sB[512], cur[512];
    const int h = blockIdx.x, tid = threadIdx.x;
    const int s0 = bb[h], s1 = bb[h + 1];
    for (int k = tid; k < 512; k += 256) sA[k] = 0;
    __syncthreads();
    for (int i = s0 + tid; i < s1; i += 256) {
        int key = (int)(pairs[i] >> 32);
        atomicAdd(&sA[key & 511], 1);
    }
    __syncthreads();
    int *src = sA, *dst = sB;
    for (int st = 1; st < 512; st <<= 1) {
        for (int k = tid; k < 512; k += 256) dst[k] = src[k] + ((k >= st) ? src[k - st] : 0);
        __syncthreads();
        int* tp = src; src = dst; dst = tp;
    }
    // src = inclusive scan
    for (int k = tid; k < 512; k += 256) {
        int incl = src[k];
        int excl = (k > 0) ? src[k - 1] : 0;
        cur[k] = s0 + excl;
        int gkey = h * 512 + k;
        if (gkey <= 2 * NN) offsets[gkey] = s0 + excl;
        if (gkey < 2 * NN) {
            int cnt = incl - excl;
            inv[gkey] = (cnt > 0) ? rsqrtf((float)cnt) : 0.0f;
        }
    }
    __syncthreads();
    for (int i = s0 + tid; i < s1; i += 256) {
        unsigned long long p = pairs[i];
        int key = (int)(p >> 32);
        int pos = atomicAdd(&cur[key & 511], 1);
        csr_src[pos] = (int)(unsigned)(p & 0xffffffffULL);
    }
}

// Fused gather + GEMM: R8's residency geometry x R9's dual-stream MLP.
// Block = 512 threads (8 waves), 32 nodes, grid 3125 (proven ~76% occupancy).
// Gather: 32 groups of 16 lanes; group g owns segments g and g+32, processed
// INTERLEAVED 4+4 -> 8 independent row-load chains in flight per group.
// LDS [32][264]: 528B rows, u16x8 ops 16B-aligned, row-step = 4 banks.
// GEMM: 16 tiles (2 row x 8 col) over 8 waves, 2 col-tiles/wave.
__global__ __launch_bounds__(512) void k_gather_gemm(
    const u16x8* __restrict__ xb8, const int* __restrict__ offsets,
    const int* __restrict__ csr_src, const float* __restrict__ inv,
    const unsigned short* __restrict__ wt, const float* __restrict__ bias,
    float* __restrict__ out) {
    __shared__ unsigned short a_lds[32][264];

    const int g = threadIdx.x >> 4;            // 0..31
    const int cl = threadIdx.x & 15;
    const int n0 = blockIdx.x * 32;            // 3125*32 == NN exactly

    // segment A = g, segment B = g+32   (seg -> node seg>>1, dir seg&1)
    const int nlA = g >> 1;
    const int nlB = 16 + (g >> 1);
    const int dir = g & 1;
    const int nA = n0 + nlA, nB = n0 + nlB;

    int eA = offsets[dir * NN + nA], endA = offsets[dir * NN + nA + 1];
    int eB = offsets[dir * NN + nB], endB = offsets[dir * NN + nB + 1];
    const float* __restrict__ srcinv = inv + (dir ^ 1) * NN;

    f32x8 accA = {0.f, 0.f, 0.f, 0.f, 0.f, 0.f, 0.f, 0.f};
    f32x8 accB = {0.f, 0.f, 0.f, 0.f, 0.f, 0.f, 0.f, 0.f};

    // interleaved main loop: 8 outstanding row loads per group
    while (eA + 4 <= endA && eB + 4 <= endB) {
        int a0 = csr_src[eA], a1 = csr_src[eA + 1], a2 = csr_src[eA + 2], a3 = csr_src[eA + 3];
        int b0 = csr_src[eB], b1 = csr_src[eB + 1], b2 = csr_src[eB + 2], b3 = csr_src[eB + 3];
        float wa0 = srcinv[a0], wa1 = srcinv[a1], wa2 = srcinv[a2], wa3 = srcinv[a3];
        float wb0 = srcinv[b0], wb1 = srcinv[b1], wb2 = srcinv[b2], wb3 = srcinv[b3];
        u16x8 va0 = xb8[a0 * 16 + cl];
        u16x8 va1 = xb8[a1 * 16 + cl];
        u16x8 va2 = xb8[a2 * 16 + cl];
        u16x8 va3 = xb8[a3 * 16 + cl];
        u16x8 vb0 = xb8[b0 * 16 + cl];
        u16x8 vb1 = xb8[b1 * 16 + cl];
        u16x8 vb2 = xb8[b2 * 16 + cl];
        u16x8 vb3 = xb8[b3 * 16 + cl];
        accA += wa0 * bvec2f(va0);
        accA += wa1 * bvec2f(va1);
        accA += wa2 * bvec2f(va2);
        accA += wa3 * bvec2f(va3);
        accB += wb0 * bvec2f(vb0);
        accB += wb1 * bvec2f(vb1);
        accB += wb2 * bvec2f(vb2);
        accB += wb3 * bvec2f(vb3);
        eA += 4; eB += 4;
    }
    // drain A
    for (; eA + 4 <= endA; eA += 4) {
        int a0 = csr_src[eA], a1 = csr_src[eA + 1], a2 = csr_src[eA + 2], a3 = csr_src[eA + 3];
        float w0 = srcinv[a0], w1 = srcinv[a1], w2 = srcinv[a2], w3 = srcinv[a3];
        u16x8 v0 = xb8[a0 * 16 + cl];
        u16x8 v1 = xb8[a1 * 16 + cl];
        u16x8 v2 = xb8[a2 * 16 + cl];
        u16x8 v3 = xb8[a3 * 16 + cl];
        accA += w0 * bvec2f(v0);
        accA += w1 * bvec2f(v1);
        accA += w2 * bvec2f(v2);
        accA += w3 * bvec2f(v3);
    }
    for (; eA < endA; ++eA) {
        int a0 = csr_src[eA];
        float w0 = srcinv[a0];
        u16x8 v0 = xb8[a0 * 16 + cl];
        accA += w0 * bvec2f(v0);
    }
    // drain B
    for (; eB + 4 <= endB; eB += 4) {
        int b0 = csr_src[eB], b1 = csr_src[eB + 1], b2 = csr_src[eB + 2], b3 = csr_src[eB + 3];
        float w0 = srcinv[b0], w1 = srcinv[b1], w2 = srcinv[b2], w3 = srcinv[b3];
        u16x8 v0 = xb8[b0 * 16 + cl];
        u16x8 v1 = xb8[b1 * 16 + cl];
        u16x8 v2 = xb8[b2 * 16 + cl];
        u16x8 v3 = xb8[b3 * 16 + cl];
        accB += w0 * bvec2f(v0);
        accB += w1 * bvec2f(v1);
        accB += w2 * bvec2f(v2);
        accB += w3 * bvec2f(v3);
    }
    for (; eB < endB; ++eB) {
        int b0 = csr_src[eB];
        float w0 = srcinv[b0];
        u16x8 v0 = xb8[b0 * 16 + cl];
        accB += w0 * bvec2f(v0);
    }

    {
        float dsA = 0.5f * inv[dir * NN + nA];
        u16x8 oA;
#pragma unroll
        for (int j = 0; j < 8; ++j) oA[j] = f2bf(accA[j] * dsA);
        *(u16x8*)&a_lds[nlA][dir * 128 + cl * 8] = oA;
        float dsB = 0.5f * inv[dir * NN + nB];
        u16x8 oB;
#pragma unroll
        for (int j = 0; j < 8; ++j) oB[j] = f2bf(accB[j] * dsB);
        *(u16x8*)&a_lds[nlB][dir * 128 + cl * 8] = oB;
    }
    __syncthreads();

    // GEMM phase: wave w -> row-tile (w&1), col-tiles (w>>1)*2 .. +1
    const int wave = threadIdx.x >> 6;
    const int lane = threadIdx.x & 63;
    const int fr = lane & 15;
    const int kg = (lane >> 4) * 8;
    const int rt = wave & 1;
    const int ct0 = (wave >> 1) * 2;

    f32x4 acc[2] = {};
#pragma unroll
    for (int s = 0; s < 8; ++s) {
        short8 afrag = *(const short8*)&a_lds[rt * 16 + fr][s * 32 + kg];
#pragma unroll
        for (int c = 0; c < 2; ++c) {
            short8 bfrag = *(const short8*)(wt + ((ct0 + c) * 16 + fr) * 256 + s * 32 + kg);
            acc[c] = __builtin_amdgcn_mfma_f32_16x16x32_bf16(afrag, bfrag, acc[c], 0, 0, 0);
        }
    }

    const int orow0 = n0 + rt * 16 + (lane >> 4) * 4;
#pragma unroll
    for (int c = 0; c < 2; ++c) {
        const int col = (ct0 + c) * 16 + fr;
        const float b = bias[col];
#pragma unroll
        for (int i = 0; i < 4; ++i) {
            out[(orow0 + i) * 128 + col] = acc[c][i] + b;
        }
    }
}

extern "C" void kernel_launch(void* const* d_in, const int* in_sizes, int n_in,
                              void* d_out, int out_size, void* d_ws, size_t ws_size,
                              hipStream_t stream) {
    const float* x   = (const float*)d_in[0];
    const int* ei    = (const int*)d_in[1];
    const float* Wsd = (const float*)d_in[2];
    const float* bsd = (const float*)d_in[3];
    const float* Wds = (const float*)d_in[4];
    const float* bds = (const float*)d_in[5];

    char* ws = (char*)d_ws;
    float* inv     = (float*)(ws + OFF_INV);
    int*   offsets = (int*)(ws + OFF_OFFS);
    int*   bb      = (int*)(ws + OFF_BB);
    int*   hist    = (int*)(ws + OFF_HIST);
    int*   csr_src = (int*)(ws + OFF_CSRC);
    unsigned short* xb  = (unsigned short*)(ws + OFF_XB);
    unsigned long long* pairs = (unsigned long long*)(ws + OFF_PAIRS);
    unsigned short* wt  = (unsigned short*)(ws + OFF_WT);
    float* bias    = (float*)(ws + OFF_BIAS);
    int*   tot     = (int*)(ws + OFF_TOT);

    k_prep<<<GB_CVT + GB_PW + GB_HIST, 256, 0, stream>>>(
        (const float4*)x, (ushort4*)xb, Wds, Wsd, bds, bsd, wt, bias, ei, hist);
    k_red<<<NB, 256, 0, stream>>>(hist, tot);
    k_scan_tot<<<1, 512, 0, stream>>>(tot, bb);
    k_rebase<<<NB, 256, 0, stream>>>(hist, bb);
    k_scatter<<<256, 256, 0, stream>>>(ei, hist, pairs);
    k_bucket<<<NB, 256, 0, stream>>>(pairs, bb, csr_src, offsets, inv);
    k_gather_gemm<<<NN / 32, 512, 0, stream>>>((const u16x8*)xb, offsets, csr_src, inv,
                                               wt, bias, (float*)d_out);
}

// Round 11
// 177.159 us; speedup vs baseline: 1.1971x; 1.1971x over previous
//
#include <hip/hip_runtime.h>

#define NN 100000
#define NE 800000
#define NI 1600000      // items = 2E (both directions)
#define NB 391          // coarse buckets = ceil(2N / 512)
#define IPB 6250        // items per block in hist/scatter (256 blocks)

// grid split for fused prep kernel
#define GB_CVT 12500    // cvt_x blocks (NN*32 float4 / 256)
#define GB_PW  128      // prep_w blocks
#define GB_HIST 256     // hist blocks

// ---- workspace layout (bytes) ----
#define OFF_INV    0u           // float[2N]   [0,N)=row-keyed inv, [N,2N)=col-keyed inv
#define OFF_OFFS   800000u      // int[2N+1]
#define OFF_BB     1600008u     // int[NB+1]
#define OFF_HIST   1601600u     // int[NB*256]
#define OFF_CSRC   2001984u     // int[2E]
#define OFF_XB     8401984u     // bf16[N*128]
#define OFF_PAIRS  34001984u    // ulong[2E]
#define OFF_WT     85201984u    // bf16[128*256] WT[c][k]: k<128 -> W_ds, else W_sd
#define OFF_BIAS   85267520u    // float[128] 0.5*(b_ds+b_sd)
#define OFF_TOT    85268032u    // int[NB]

typedef short short8 __attribute__((ext_vector_type(8)));
typedef unsigned short u16x8 __attribute__((ext_vector_type(8)));
typedef float f32x4 __attribute__((ext_vector_type(4)));
typedef float f32x8 __attribute__((ext_vector_type(8)));

__device__ __forceinline__ unsigned short f2bf(float f) {
    unsigned u = __float_as_uint(f);
    u = (u + 0x7FFFu + ((u >> 16) & 1u)) >> 16;   // RNE
    return (unsigned short)u;
}
__device__ __forceinline__ float b2f(unsigned short h) {
    return __uint_as_float(((unsigned)h) << 16);
}
__device__ __forceinline__ f32x8 bvec2f(u16x8 v) {
    f32x8 r;
#pragma unroll
    for (int i = 0; i < 8; ++i) r[i] = b2f(v[i]);
    return r;
}

// item i: i<NE  -> key=row=ei[i],      val=col=ei[NE+i]  (in-agg, keyed by row)
//         i>=NE -> key=NN+col=NN+ei[i], val=row=ei[i-NE] (out-agg, keyed by col)

// Fused: cvt_x (blocks [0,GB_CVT)) | prep_w | hist  — mutually independent work
__global__ __launch_bounds__(256) void k_prep(
    const float4* __restrict__ x4, ushort4* __restrict__ xb4,
    const float* __restrict__ Wds, const float* __restrict__ Wsd,
    const float* __restrict__ bds, const float* __restrict__ bsd,
    unsigned short* __restrict__ wt, float* __restrict__ bias,
    const int* __restrict__ ei, int* __restrict__ hist) {
    __shared__ int h[NB];
    int bid = blockIdx.x;
    if (bid < GB_CVT) {
        int i = bid * 256 + threadIdx.x;           // < NN*32 exactly
        float4 v = x4[i];
        ushort4 o;
        o.x = f2bf(v.x); o.y = f2bf(v.y); o.z = f2bf(v.z); o.w = f2bf(v.w);
        xb4[i] = o;
        return;
    }
    if (bid < GB_CVT + GB_PW) {
        int id = (bid - GB_CVT) * 256 + threadIdx.x;   // < 32768 exactly
        int c = id & 127;
        int k = id >> 7;
        float v = (k < 128) ? Wds[k * 128 + c] : Wsd[(k - 128) * 128 + c];
        wt[c * 256 + k] = f2bf(v);
        if (k == 0) bias[c] = 0.5f * (bds[c] + bsd[c]);
        return;
    }
    int hb = bid - GB_CVT - GB_PW;                  // hist block 0..255
    for (int k = threadIdx.x; k < NB; k += 256) h[k] = 0;
    __syncthreads();
    int base = hb * IPB;
    for (int t = threadIdx.x; t < IPB; t += 256) {
        int i = base + t;
        int key = (i < NE) ? ei[i] : (NN + ei[i]);
        atomicAdd(&h[key >> 9], 1);
    }
    __syncthreads();
    for (int k = threadIdx.x; k < NB; k += 256) hist[k * 256 + hb] = h[k];
}

// Per-bucket column scan: hist[k][b] -> exclusive scan over b (LOCAL), tot[k] = total.
// Replaces k_red + k_rebase (one pass instead of two + no rewrite pass later).
__global__ __launch_bounds__(256) void k_colscan(int* __restrict__ hist,
                                                 int* __restrict__ tot) {
    __shared__ int sA[256], sB[256];
    int k = blockIdx.x, tid = threadIdx.x;
    int v = hist[k * 256 + tid];
    sA[tid] = v;
    __syncthreads();
    int *src = sA, *dst = sB;
    for (int st = 1; st < 256; st <<= 1) {
        dst[tid] = src[tid] + ((tid >= st) ? src[tid - st] : 0);
        __syncthreads();
        int* tp = src; src = dst; dst = tp;
    }
    hist[k * 256 + tid] = src[tid] - v;   // local exclusive scan
    if (tid == 255) tot[k] = src[255];
}

// bb = exclusive scan of tot (NB entries, padded to 512)
__global__ __launch_bounds__(512) void k_scan_tot(const int* __restrict__ tot,
                                                  int* __restrict__ bb) {
    __shared__ int sA[512], sB[512];
    int tid = threadIdx.x;
    int v = (tid < NB) ? tot[tid] : 0;
    sA[tid] = v;
    __syncthreads();
    int *src = sA, *dst = sB;
    for (int st = 1; st < 512; st <<= 1) {
        dst[tid] = src[tid] + ((tid >= st) ? src[tid - st] : 0);
        __syncthreads();
        int* tp = src; src = dst; dst = tp;
    }
    if (tid <= NB) bb[tid] = (tid > 0) ? src[tid - 1] : 0;
}

// scatter into pairs; cursor base = global bucket base + local (per-block) base
__global__ __launch_bounds__(256) void k_scatter(const int* __restrict__ ei,
                                                 const int* __restrict__ hist,
                                                 const int* __restrict__ bb,
                                                 unsigned long long* __restrict__ pairs) {
    __shared__ int cur[NB];
    for (int k = threadIdx.x; k < NB; k += 256)
        cur[k] = bb[k] + hist[k * 256 + blockIdx.x];
    __syncthreads();
    int base = blockIdx.x * IPB;
    for (int t = threadIdx.x; t < IPB; t += 256) {
        int i = base + t;
        int e = ei[i];
        int key, val;
        if (i < NE) { key = e;      val = ei[NE + i]; }
        else        { key = NN + e; val = ei[i - NE]; }
        int pos = atomicAdd(&cur[key >> 9], 1);
        pairs[pos] = (((unsigned long long)(unsigned)key) << 32) | (unsigned)val;
    }
}

// one block per bucket: count 512 local keys, scan, emit offsets+inv, scatter vals
__global__ __launch_bounds__(256) void k_bucket(const unsigned long long* __restrict__ pairs,
                                                const int* __restrict__ bb,
                                                int* __restrict__ csr_src,
                                                int* __restrict__ offsets,
                                                float* __restrict__ inv) {
    __shared__ int sA[512], sB[512], cur[512];
    const int h = blockIdx.x, tid = threadIdx.x;
    const int s0 = bb[h], s1 = bb[h + 1];
    for (int k = tid; k < 512; k += 256) sA[k] = 0;
    __syncthreads();
    for (int i = s0 + tid; i < s1; i += 256) {
        int key = (int)(pairs[i] >> 32);
        atomicAdd(&sA[key & 511], 1);
    }
    __syncthreads();
    int *src = sA, *dst = sB;
    for (int st = 1; st < 512; st <<= 1) {
        for (int k = tid; k < 512; k += 256) dst[k] = src[k] + ((k >= st) ? src[k - st] : 0);
        __syncthreads();
        int* tp = src; src = dst; dst = tp;
    }
    // src = inclusive scan
    for (int k = tid; k < 512; k += 256) {
        int incl = src[k];
        int excl = (k > 0) ? src[k - 1] : 0;
        cur[k] = s0 + excl;
        int gkey = h * 512 + k;
        if (gkey <= 2 * NN) offsets[gkey] = s0 + excl;
        if (gkey < 2 * NN) {
            int cnt = incl - excl;
            inv[gkey] = (cnt > 0) ? rsqrtf((float)cnt) : 0.0f;
        }
    }
    __syncthreads();
    for (int i = s0 + tid; i < s1; i += 256) {
        unsigned long long p = pairs[i];
        int key = (int)(p >> 32);
        int pos = atomicAdd(&cur[key & 511], 1);
        csr_src[pos] = (int)(unsigned)(p & 0xffffffffULL);
    }
}

// Fused gather + GEMM — R6's proven-optimal geometry (117 us, 81% occ):
// Block = 512 threads (8 waves), 16 nodes, 32 segments, grid 6250.
// Gather: 32 groups of 16 lanes, 1 segment each, 4-deep unrolled row loads.
// LDS [16][264]: 528B rows, u16x8 ops 16B-aligned. 8.4 KB/block.
// GEMM: wave w computes col-tile w (16 cols x 16 rows), K=256.
__global__ __launch_bounds__(512) void k_gather_gemm(
    const u16x8* __restrict__ xb8, const int* __restrict__ offsets,
    const int* __restrict__ csr_src, const float* __restrict__ inv,
    const unsigned short* __restrict__ wt, const float* __restrict__ bias,
    float* __restrict__ out) {
    __shared__ unsigned short a_lds[16][264];

    const int wave = threadIdx.x >> 6;
    const int lane = threadIdx.x & 63;
    const int grp = lane >> 4;                 // 0..3
    const int cl = lane & 15;
    const int nl = wave * 2 + (grp >> 1);      // local node 0..15
    const int n = blockIdx.x * 16 + nl;        // 6250*16 == NN exactly
    const int dir = grp & 1;                   // 0 = in-agg, 1 = out-agg

    {
        int key = dir * NN + n;
        int s0 = offsets[key], s1 = offsets[key + 1];
        const float* __restrict__ srcinv = inv + (dir ^ 1) * NN;

        f32x8 acc = {0.f, 0.f, 0.f, 0.f, 0.f, 0.f, 0.f, 0.f};
        int e = s0;
        for (; e + 4 <= s1; e += 4) {
            int i0 = csr_src[e];
            int i1 = csr_src[e + 1];
            int i2 = csr_src[e + 2];
            int i3 = csr_src[e + 3];
            float w0 = srcinv[i0], w1 = srcinv[i1], w2 = srcinv[i2], w3 = srcinv[i3];
            u16x8 v0 = xb8[i0 * 16 + cl];
            u16x8 v1 = xb8[i1 * 16 + cl];
            u16x8 v2 = xb8[i2 * 16 + cl];
            u16x8 v3 = xb8[i3 * 16 + cl];
            acc += w0 * bvec2f(v0);
            acc += w1 * bvec2f(v1);
            acc += w2 * bvec2f(v2);
            acc += w3 * bvec2f(v3);
        }
        for (; e < s1; ++e) {
            int i0 = csr_src[e];
            float w0 = srcinv[i0];
            u16x8 v0 = xb8[i0 * 16 + cl];
            acc += w0 * bvec2f(v0);
        }

        float ds = 0.5f * inv[dir * NN + n];       // dest-side scale + ALPHA fold
        u16x8 o;
#pragma unroll
        for (int i = 0; i < 8; ++i) o[i] = f2bf(acc[i] * ds);
        *(u16x8*)&a_lds[nl][dir * 128 + cl * 8] = o;
    }
    __syncthreads();

    // GEMM: this wave's 16x16 output tile, cols [wave*16, wave*16+16)
    const int fr = lane & 15;
    const int kg = (lane >> 4) * 8;
    const int col = wave * 16 + fr;

    f32x4 acc = {};
#pragma unroll
    for (int s = 0; s < 8; ++s) {
        short8 afrag = *(const short8*)&a_lds[fr][s * 32 + kg];
        short8 bfrag = *(const short8*)(wt + col * 256 + s * 32 + kg);
        acc = __builtin_amdgcn_mfma_f32_16x16x32_bf16(afrag, bfrag, acc, 0, 0, 0);
    }

    const float b = bias[col];
    const int orow0 = blockIdx.x * 16 + (lane >> 4) * 4;
#pragma unroll
    for (int i = 0; i < 4; ++i) {
        out[(orow0 + i) * 128 + col] = acc[i] + b;
    }
}

extern "C" void kernel_launch(void* const* d_in, const int* in_sizes, int n_in,
                              void* d_out, int out_size, void* d_ws, size_t ws_size,
                              hipStream_t stream) {
    const float* x   = (const float*)d_in[0];
    const int* ei    = (const int*)d_in[1];
    const float* Wsd = (const float*)d_in[2];
    const float* bsd = (const float*)d_in[3];
    const float* Wds = (const float*)d_in[4];
    const float* bds = (const float*)d_in[5];

    char* ws = (char*)d_ws;
    float* inv     = (float*)(ws + OFF_INV);
    int*   offsets = (int*)(ws + OFF_OFFS);
    int*   bb      = (int*)(ws + OFF_BB);
    int*   hist    = (int*)(ws + OFF_HIST);
    int*   csr_src = (int*)(ws + OFF_CSRC);
    unsigned short* xb  = (unsigned short*)(ws + OFF_XB);
    unsigned long long* pairs = (unsigned long long*)(ws + OFF_PAIRS);
    unsigned short* wt  = (unsigned short*)(ws + OFF_WT);
    float* bias    = (float*)(ws + OFF_BIAS);
    int*   tot     = (int*)(ws + OFF_TOT);

    k_prep<<<GB_CVT + GB_PW + GB_HIST, 256, 0, stream>>>(
        (const float4*)x, (ushort4*)xb, Wds, Wsd, bds, bsd, wt, bias, ei, hist);
    k_colscan<<<NB, 256, 0, stream>>>(hist, tot);
    k_scan_tot<<<1, 512, 0, stream>>>(tot, bb);
    k_scatter<<<256, 256, 0, stream>>>(ei, hist, bb, pairs);
    k_bucket<<<NB, 256, 0, stream>>>(pairs, bb, csr_src, offsets, inv);
    k_gather_gemm<<<NN / 16, 512, 0, stream>>>((const u16x8*)xb, offsets, csr_src, inv,
                                               wt, bias, (float*)d_out);
}